// Round 13
// baseline (414.923 us; speedup 1.0000x reference)
//
#include <hip/hip_runtime.h>

typedef __attribute__((ext_vector_type(8))) short short8;
typedef __attribute__((ext_vector_type(4))) float f32x4;
typedef __attribute__((ext_vector_type(4))) unsigned short u16x4;

#define GLOAD16(g, l)                                                          \
  __builtin_amdgcn_global_load_lds(                                            \
      (const __attribute__((address_space(1))) unsigned int*)(g),              \
      (__attribute__((address_space(3))) unsigned int*)(l), 16, 0, 0)

__device__ __forceinline__ unsigned short f2bf(float f) {
  unsigned int u = __float_as_uint(f);
  u += 0x7FFFu + ((u >> 16) & 1u);   // RNE
  return (unsigned short)(u >> 16);
}
__device__ __forceinline__ float bf2f(unsigned short h) {
  return __uint_as_float(((unsigned int)h) << 16);
}

// ---------------------------------------------------------------- mix / bmix
__global__ void mix_kernel(const float* __restrict__ amp,
                           const float* __restrict__ phase,
                           const float* __restrict__ bias,
                           float* __restrict__ mix, float* __restrict__ bmix) {
  int q = blockIdx.x * blockDim.x + threadIdx.x;  // 0..1023
  float a[16];
  float mx = -1e30f;
  for (int s = 0; s < 16; ++s) {
    a[s] = amp[s * 1024 + q];
    mx = fmaxf(mx, a[s]);
  }
  float sum = 0.f;
  for (int s = 0; s < 16; ++s) {
    a[s] = __expf(a[s] - mx);
    sum += a[s];
  }
  float inv = 1.f / sum;
  for (int s = 0; s < 16; ++s) {
    float m = a[s] * inv * cosf(phase[s * 1024 + q]);
    mix[s * 1024 + q] = m;
    bmix[s * 1024 + q] = bias[s * 1024 + q] * m;
  }
}

// ---------------------------------------------------------------- cast x->bf16
__global__ void cast_x_kernel(const float* __restrict__ x,
                              unsigned short* __restrict__ xb) {
  int i = (blockIdx.x * blockDim.x + threadIdx.x) * 4;
  float4 v = *(const float4*)(x + i);
  union { unsigned short h[4]; uint2 u; } o;
  o.h[0] = f2bf(v.x); o.h[1] = f2bf(v.y); o.h[2] = f2bf(v.z); o.h[3] = f2bf(v.w);
  *(uint2*)(xb + i) = o.u;
}

// ------------------------------------------- transpose+cast+scale W -> Wt bf16
// Wt[s][q][i] = bf16( W[s][i][q] * mix[s][q] ).  float4 reads (16B/lane),
// packed uint2 LDS writes, short8 global writes (128B contiguous per q-row).
__global__ __launch_bounds__(256) void transpose_w_kernel(
    const float* __restrict__ W, const float* __restrict__ mix,
    unsigned short* __restrict__ Wt) {
  __shared__ unsigned short tile[64][68];   // 68-short row = 17 dwords, coprime 32
  const int s = blockIdx.z;
  const int q0 = blockIdx.x * 64, i0 = blockIdx.y * 64;
  const int t = threadIdx.x;
  const float* Ws = W + (size_t)s * 1048576;
  unsigned short* Wts = Wt + (size_t)s * 1048576;
  const int rq = (t & 15) * 4;
  const int ri = t >> 4;                    // 0..15
  const float4 mv = *(const float4*)(mix + s * 1024 + q0 + rq);
  #pragma unroll
  for (int p = 0; p < 4; ++p) {
    const int i = p * 16 + ri;
    float4 v = *(const float4*)(Ws + (size_t)(i0 + i) * 1024 + q0 + rq);
    union { unsigned short h[4]; uint2 u; } pk;
    pk.h[0] = f2bf(v.x * mv.x);
    pk.h[1] = f2bf(v.y * mv.y);
    pk.h[2] = f2bf(v.z * mv.z);
    pk.h[3] = f2bf(v.w * mv.w);
    *(uint2*)&tile[i][rq] = pk.u;
  }
  __syncthreads();
  const int wq = t >> 2;                    // 0..63
  const int wi = (t & 3) * 16;              // 0,16,32,48
  union { unsigned short h[8]; short8 v8; } u0, u1;
  #pragma unroll
  for (int e = 0; e < 8; ++e) {
    u0.h[e] = tile[wi + e][wq];
    u1.h[e] = tile[wi + 8 + e][wq];
  }
  unsigned short* dst = Wts + (size_t)(q0 + wq) * 1024 + i0 + wi;
  *(short8*)dst = u0.v8;
  *(short8*)(dst + 8) = u1.v8;
}

// ---------------------------------------------------------------- bf16 GEMM
// R13: A direct global->VGPR (no A LDS), B via 3-buffer LDS.  128x128 tile,
// BK=32, 4 waves (2x2).  LDS 24KB (was 48).  Per sub-step:
//   RDB(kt) ; SB(kt+2)[2 gload_lds] ; lgkmcnt(0) ; vmcnt(2) ; barrier ;
//   MFMA(kt) ; LA(kt+2) -> same A reg set (WAR-safe: after MFMAs issued)
// Rolling vmcnt(2) confirms tile kt+1's SB(2)+LA(4) (issued one sub-step
// earlier; a full step of MFMA covers the latency).  B-buf WAR: reads of a
// buffer drain at lgkmcnt(0) >=1 barrier before the overwriting SB (barrier
// joins all waves).  Prologue vmcnt(4); tail kt=30 vmcnt(0); kt=31 no wait.
template <bool BF16SUP>
__global__ __launch_bounds__(256) void gemm_kernel(
    const unsigned short* __restrict__ xb, const unsigned short* __restrict__ wt,
    const float* __restrict__ bmix,
    float* __restrict__ outf, unsigned short* __restrict__ sup) {
  __shared__ __align__(16) unsigned short Bbuf[3][128 * 32];

  const int tid = threadIdx.x;
  const int lane = tid & 63;
  const int wv = tid >> 6;
  const int wm = wv >> 1, wn = wv & 1;
  const int m0 = blockIdx.y * 128;
  const int n0 = blockIdx.x * 128;

  const int lr = lane & 15;
  const int lk = (lane >> 4) * 8;

  // B staging geometry: chunk c covers row c>>2, 8 bf16 at col (c&3)*8
  const int c0 = tid, c1 = tid + 256;
  const int r0 = c0 >> 2, k80 = (c0 & 3) * 8;
  const int r1 = c1 >> 2, k81 = (c1 & 3) * 8;
  const unsigned short* gb0 = wt + (size_t)(n0 + r0) * 1024 + k80;
  const unsigned short* gb1 = wt + (size_t)(n0 + r1) * 1024 + k81;
  // A direct-load base: row m0+wm*64+lr, k-chunk lk
  const unsigned short* pA = xb + (size_t)(m0 + wm * 64 + lr) * 1024 + lk;

#define SB(kt, b) do {                                                         \
    const int _ko = (kt) * 32;                                                 \
    GLOAD16(gb0 + _ko, &Bbuf[b][c0 * 8]);                                      \
    GLOAD16(gb1 + _ko, &Bbuf[b][c1 * 8]);                                      \
  } while (0)

#define LA(kt, DST) do {                                                       \
    _Pragma("unroll")                                                          \
    for (int mi = 0; mi < 4; ++mi)                                             \
      DST[mi] = *(const short8*)(pA + (size_t)mi * 16384 + (kt) * 32);         \
  } while (0)

#define RDB(BF, b) do {                                                        \
    const unsigned short* _bb = &Bbuf[b][(wn * 64 + lr) * 32 + lk];            \
    _Pragma("unroll")                                                          \
    for (int ni = 0; ni < 4; ++ni)                                             \
      BF[ni] = *(const short8*)(_bb + ni * 16 * 32);                           \
  } while (0)

#define MFMASET(AF, BF)                                                        \
    _Pragma("unroll")                                                          \
    for (int mi = 0; mi < 4; ++mi)                                             \
      _Pragma("unroll")                                                        \
      for (int ni = 0; ni < 4; ++ni)                                           \
        acc[mi][ni] = __builtin_amdgcn_mfma_f32_16x16x32_bf16(                 \
            AF[mi], BF[ni], acc[mi][ni], 0, 0, 0)

  f32x4 acc[4][4];
  #pragma unroll
  for (int i = 0; i < 4; ++i)
    #pragma unroll
    for (int j = 0; j < 4; ++j) acc[i][j] = (f32x4){0.f, 0.f, 0.f, 0.f};

  short8 aE[4], aO[4], bq[4];

  // prologue: B tiles 0,1 staged; A tiles 0,1 to regs; wait B0+A0 (LA1 flies)
  SB(0, 0);
  SB(1, 1);
  LA(0, aE);
  LA(1, aO);
  asm volatile("s_waitcnt vmcnt(4)" ::: "memory");
  __builtin_amdgcn_s_barrier();

  int b0 = 0;   // buffer of tile kt0 (= 2*it mod 3)
  #pragma unroll 1
  for (int it = 0; it < 16; ++it) {
    const int kt0 = 2 * it, kt1 = kt0 + 1;
    int b1 = b0 + 1; if (b1 >= 3) b1 -= 3;
    int b2 = b0 + 2; if (b2 >= 3) b2 -= 3;
    // --- even sub-step: compute kt0 (A set E)
    RDB(bq, b0);
    if (kt0 < 30) SB(kt0 + 2, b2);
    asm volatile("s_waitcnt lgkmcnt(0)" ::: "memory");
    if (kt0 < 30) asm volatile("s_waitcnt vmcnt(2)" ::: "memory");
    else          asm volatile("s_waitcnt vmcnt(0)" ::: "memory");
    __builtin_amdgcn_sched_barrier(0);
    __builtin_amdgcn_s_barrier();
    MFMASET(aE, bq);
    if (kt0 < 30) LA(kt0 + 2, aE);
    // --- odd sub-step: compute kt1 (A set O)
    RDB(bq, b1);
    if (kt1 < 30) SB(kt1 + 2, b0);
    asm volatile("s_waitcnt lgkmcnt(0)" ::: "memory");
    if (kt1 < 30) asm volatile("s_waitcnt vmcnt(2)" ::: "memory");
    __builtin_amdgcn_sched_barrier(0);
    __builtin_amdgcn_s_barrier();
    MFMASET(aO, bq);
    if (kt1 < 30) LA(kt1 + 2, aO);
    b0 = b2;   // tiles advance by 2 per iteration
  }
#undef SB
#undef LA
#undef RDB
#undef MFMASET

  // epilogue: sup = acc + bmix  (mix folded into Wt)
  #pragma unroll
  for (int ni = 0; ni < 4; ++ni) {
    const int n = n0 + wn * 64 + ni * 16 + lr;
    const float bv = bmix[n];
    #pragma unroll
    for (int mi = 0; mi < 4; ++mi) {
      const int m = m0 + wm * 64 + mi * 16 + (lane >> 4) * 4;
      #pragma unroll
      for (int r = 0; r < 4; ++r) {
        float v = acc[mi][ni][r] + bv;
        if (BF16SUP)
          sup[(size_t)(m + r) * 16384 + n] = f2bf(v);
        else
          outf[(size_t)(m + r) * 16384 + n] = v;
      }
    }
  }
}

// ------------------------------------------------------- LN from bf16 sup
__global__ __launch_bounds__(256) void ln_bf16_kernel(
    const unsigned short* __restrict__ sup, float* __restrict__ out,
    const float* __restrict__ gamma, const float* __restrict__ beta) {
  __shared__ float red[8];
  const int t = threadIdx.x;
  const size_t base = (size_t)blockIdx.x * 1024;
  u16x4 raw = *(const u16x4*)(sup + base + t * 4);
  float v[4];
  #pragma unroll
  for (int j = 0; j < 4; ++j) v[j] = bf2f(raw[j]);
  float s = v[0] + v[1] + v[2] + v[3];
  float ss = v[0] * v[0] + v[1] * v[1] + v[2] * v[2] + v[3] * v[3];
  #pragma unroll
  for (int m = 32; m >= 1; m >>= 1) {
    s += __shfl_xor(s, m);
    ss += __shfl_xor(ss, m);
  }
  const int wv = t >> 6;
  if ((t & 63) == 0) { red[wv * 2] = s; red[wv * 2 + 1] = ss; }
  __syncthreads();
  const float S = red[0] + red[2] + red[4] + red[6];
  const float SS = red[1] + red[3] + red[5] + red[7];
  const float mean = S * (1.0f / 1024.0f);
  const float var = SS * (1.0f / 1024.0f) - mean * mean;
  const float rstd = rsqrtf(var + 1e-5f);
  const float4 g = *(const float4*)(gamma + t * 4);
  const float4 b = *(const float4*)(beta + t * 4);
  float4 o;
  o.x = (v[0] - mean) * rstd * g.x + b.x;
  o.y = (v[1] - mean) * rstd * g.y + b.y;
  o.z = (v[2] - mean) * rstd * g.z + b.z;
  o.w = (v[3] - mean) * rstd * g.w + b.w;
  *(float4*)(out + base + t * 4) = o;
}

// ------------------------------------------------------- in-place f32 LN
__global__ __launch_bounds__(256) void ln_kernel(float* __restrict__ out,
                                                 const float* __restrict__ gamma,
                                                 const float* __restrict__ beta) {
  __shared__ float red[8];
  const int t = threadIdx.x;
  const size_t base = (size_t)blockIdx.x * 1024;
  float4 v = *(const float4*)(out + base + t * 4);
  float s = v.x + v.y + v.z + v.w;
  float ss = v.x * v.x + v.y * v.y + v.z * v.z + v.w * v.w;
  #pragma unroll
  for (int m = 32; m >= 1; m >>= 1) {
    s += __shfl_xor(s, m);
    ss += __shfl_xor(ss, m);
  }
  const int wv = t >> 6;
  if ((t & 63) == 0) { red[wv * 2] = s; red[wv * 2 + 1] = ss; }
  __syncthreads();
  const float S = red[0] + red[2] + red[4] + red[6];
  const float SS = red[1] + red[3] + red[5] + red[7];
  const float mean = S * (1.0f / 1024.0f);
  const float var = SS * (1.0f / 1024.0f) - mean * mean;
  const float rstd = rsqrtf(var + 1e-5f);
  const float4 g = *(const float4*)(gamma + t * 4);
  const float4 b = *(const float4*)(beta + t * 4);
  float4 o;
  o.x = (v.x - mean) * rstd * g.x + b.x;
  o.y = (v.y - mean) * rstd * g.y + b.y;
  o.z = (v.z - mean) * rstd * g.z + b.z;
  o.w = (v.w - mean) * rstd * g.w + b.w;
  *(float4*)(out + base + t * 4) = o;
}

extern "C" void kernel_launch(void* const* d_in, const int* in_sizes, int n_in,
                              void* d_out, int out_size, void* d_ws, size_t ws_size,
                              hipStream_t stream) {
  (void)in_sizes; (void)n_in; (void)out_size;
  const float* x     = (const float*)d_in[0];  // [4096,1024]
  const float* W     = (const float*)d_in[1];  // [16,1024,1024]
  const float* bias  = (const float*)d_in[2];  // [16,1024]
  const float* amp   = (const float*)d_in[3];  // [16,1024]
  const float* phase = (const float*)d_in[4];  // [16,1024]
  const float* gamma = (const float*)d_in[5];  // [1024]
  const float* beta  = (const float*)d_in[6];  // [1024]
  float* out = (float*)d_out;                  // [4096,16,1024] = 256 MiB

  const bool big = ws_size >= (size_t)134217728ULL;  // bf16 sup fits in ws

  unsigned short *Wt, *xbuf, *supb = nullptr;
  float *mixp, *bmixp;
  if (big) {
    // scratch Wt/xb/mix live in d_out (fully rewritten by LN afterwards);
    // ws holds bf16 sup (exactly 128 MiB)
    char* ob = (char*)d_out;
    Wt    = (unsigned short*)ob;                    // 32 MiB
    xbuf  = (unsigned short*)(ob + 33554432);       //  8 MiB
    mixp  = (float*)(ob + 41943040);                // 64 KiB
    bmixp = mixp + 16384;                           // 64 KiB
    supb  = (unsigned short*)d_ws;                  // 128 MiB
  } else {
    char* ws = (char*)d_ws;
    Wt    = (unsigned short*)ws;
    xbuf  = (unsigned short*)(ws + 33554432);
    mixp  = (float*)(ws + 33554432 + 8388608);
    bmixp = mixp + 16384;
  }

  hipLaunchKernelGGL(mix_kernel, dim3(4), dim3(256), 0, stream, amp, phase, bias, mixp, bmixp);
  hipLaunchKernelGGL(cast_x_kernel, dim3(4096), dim3(256), 0, stream, x, xbuf);
  hipLaunchKernelGGL(transpose_w_kernel, dim3(16, 16, 16), dim3(256), 0, stream, W, mixp, Wt);
  if (big) {
    hipLaunchKernelGGL((gemm_kernel<true>), dim3(128, 32), dim3(256), 0, stream,
                       xbuf, Wt, bmixp, out, supb);
    hipLaunchKernelGGL(ln_bf16_kernel, dim3(65536), dim3(256), 0, stream,
                       supb, out, gamma, beta);
  } else {
    hipLaunchKernelGGL((gemm_kernel<false>), dim3(128, 32), dim3(256), 0, stream,
                       xbuf, Wt, bmixp, out, nullptr);
    hipLaunchKernelGGL(ln_kernel, dim3(65536), dim3(256), 0, stream, out, gamma, beta);
  }
}

// Round 14
// 299.421 us; speedup vs baseline: 1.3858x; 1.3858x over previous
//
#include <hip/hip_runtime.h>

typedef __attribute__((ext_vector_type(8))) short short8;
typedef __attribute__((ext_vector_type(4))) float f32x4;
typedef __attribute__((ext_vector_type(4))) unsigned short u16x4;

#define GLOAD16(g, l)                                                          \
  __builtin_amdgcn_global_load_lds(                                            \
      (const __attribute__((address_space(1))) unsigned int*)(g),              \
      (__attribute__((address_space(3))) unsigned int*)(l), 16, 0, 0)

__device__ __forceinline__ unsigned short f2bf(float f) {
  unsigned int u = __float_as_uint(f);
  u += 0x7FFFu + ((u >> 16) & 1u);   // RNE
  return (unsigned short)(u >> 16);
}
__device__ __forceinline__ float bf2f(unsigned short h) {
  return __uint_as_float(((unsigned int)h) << 16);
}

// ---------------------------------------------------------------- mix / bmix
__global__ void mix_kernel(const float* __restrict__ amp,
                           const float* __restrict__ phase,
                           const float* __restrict__ bias,
                           float* __restrict__ mix, float* __restrict__ bmix) {
  int q = blockIdx.x * blockDim.x + threadIdx.x;  // 0..1023
  float a[16];
  float mx = -1e30f;
  for (int s = 0; s < 16; ++s) {
    a[s] = amp[s * 1024 + q];
    mx = fmaxf(mx, a[s]);
  }
  float sum = 0.f;
  for (int s = 0; s < 16; ++s) {
    a[s] = __expf(a[s] - mx);
    sum += a[s];
  }
  float inv = 1.f / sum;
  for (int s = 0; s < 16; ++s) {
    float m = a[s] * inv * cosf(phase[s * 1024 + q]);
    mix[s * 1024 + q] = m;
    bmix[s * 1024 + q] = bias[s * 1024 + q] * m;
  }
}

// ---------------------------------------------------------------- cast x->bf16
__global__ void cast_x_kernel(const float* __restrict__ x,
                              unsigned short* __restrict__ xb) {
  int i = (blockIdx.x * blockDim.x + threadIdx.x) * 4;
  float4 v = *(const float4*)(x + i);
  union { unsigned short h[4]; uint2 u; } o;
  o.h[0] = f2bf(v.x); o.h[1] = f2bf(v.y); o.h[2] = f2bf(v.z); o.h[3] = f2bf(v.w);
  *(uint2*)(xb + i) = o.u;
}

// ------------------------------------------- transpose+cast+scale W -> Wt bf16
// Wt[s][q][i] = bf16( W[s][i][q] * mix[s][q] ).  float4 reads (16B/lane),
// packed uint2 LDS writes, short8 global writes (128B contiguous per q-row).
__global__ __launch_bounds__(256) void transpose_w_kernel(
    const float* __restrict__ W, const float* __restrict__ mix,
    unsigned short* __restrict__ Wt) {
  __shared__ unsigned short tile[64][68];   // 68-short row = 17 dwords, coprime 32
  const int s = blockIdx.z;
  const int q0 = blockIdx.x * 64, i0 = blockIdx.y * 64;
  const int t = threadIdx.x;
  const float* Ws = W + (size_t)s * 1048576;
  unsigned short* Wts = Wt + (size_t)s * 1048576;
  const int rq = (t & 15) * 4;
  const int ri = t >> 4;                    // 0..15
  const float4 mv = *(const float4*)(mix + s * 1024 + q0 + rq);
  #pragma unroll
  for (int p = 0; p < 4; ++p) {
    const int i = p * 16 + ri;
    float4 v = *(const float4*)(Ws + (size_t)(i0 + i) * 1024 + q0 + rq);
    union { unsigned short h[4]; uint2 u; } pk;
    pk.h[0] = f2bf(v.x * mv.x);
    pk.h[1] = f2bf(v.y * mv.y);
    pk.h[2] = f2bf(v.z * mv.z);
    pk.h[3] = f2bf(v.w * mv.w);
    *(uint2*)&tile[i][rq] = pk.u;
  }
  __syncthreads();
  const int wq = t >> 2;                    // 0..63
  const int wi = (t & 3) * 16;              // 0,16,32,48
  union { unsigned short h[8]; short8 v8; } u0, u1;
  #pragma unroll
  for (int e = 0; e < 8; ++e) {
    u0.h[e] = tile[wi + e][wq];
    u1.h[e] = tile[wi + 8 + e][wq];
  }
  unsigned short* dst = Wts + (size_t)(q0 + wq) * 1024 + i0 + wi;
  *(short8*)dst = u0.v8;
  *(short8*)(dst + 8) = u1.v8;
}

// ---------------------------------------------------------------- bf16 GEMM
// R9 configuration (best measured: 185.0us / 740 TF).  128x128 tile, BK=32,
// 4 waves (2x2), 3-buffer LDS depth-2 prefetch, raw s_barrier with counted
// vmcnt(4) held across the barrier, lgkmcnt(0) drain before barrier.
// Measured-null variants NOT included: reg ds_read prefetch (R12),
// L2 supertile map (R10), A-in-VGPR (R13), 8-phase ports (R2/R3/R4).
template <bool BF16SUP>
__global__ __launch_bounds__(256) void gemm_kernel(
    const unsigned short* __restrict__ xb, const unsigned short* __restrict__ wt,
    const float* __restrict__ bmix,
    float* __restrict__ outf, unsigned short* __restrict__ sup) {
  __shared__ __align__(16) unsigned short Abuf[3][128 * 32];
  __shared__ __align__(16) unsigned short Bbuf[3][128 * 32];

  const int tid = threadIdx.x;
  const int lane = tid & 63;
  const int wv = tid >> 6;
  const int wm = wv >> 1, wn = wv & 1;
  const int m0 = blockIdx.y * 128;
  const int n0 = blockIdx.x * 128;

  const int c0 = tid, c1 = tid + 256;
  const int r0 = c0 >> 2, k80 = (c0 & 3) * 8;
  const int r1 = c1 >> 2, k81 = (c1 & 3) * 8;
  const unsigned short* ga0 = xb + (size_t)(m0 + r0) * 1024 + k80;
  const unsigned short* ga1 = xb + (size_t)(m0 + r1) * 1024 + k81;
  const unsigned short* gb0 = wt + (size_t)(n0 + r0) * 1024 + k80;
  const unsigned short* gb1 = wt + (size_t)(n0 + r1) * 1024 + k81;

#define STAGE(kt, b) do {                                                      \
    const int _ko = (kt) * 32;                                                 \
    GLOAD16(ga0 + _ko, &Abuf[b][c0 * 8]);                                      \
    GLOAD16(ga1 + _ko, &Abuf[b][c1 * 8]);                                      \
    GLOAD16(gb0 + _ko, &Bbuf[b][c0 * 8]);                                      \
    GLOAD16(gb1 + _ko, &Bbuf[b][c1 * 8]);                                      \
  } while (0)

  f32x4 acc[4][4];
  #pragma unroll
  for (int i = 0; i < 4; ++i)
    #pragma unroll
    for (int j = 0; j < 4; ++j) acc[i][j] = (f32x4){0.f, 0.f, 0.f, 0.f};

  // prologue: stage tiles 0,1; wait tile 0 landed (tile 1 stays in flight)
  STAGE(0, 0);
  STAGE(1, 1);
  asm volatile("s_waitcnt vmcnt(4)" ::: "memory");
  __builtin_amdgcn_s_barrier();

  const int lr = lane & 15;
  const int lk = (lane >> 4) * 8;
  int cur = 0;
  for (int kt = 0; kt < 32; ++kt) {
    if (kt < 30) {
      int nb = cur + 2; if (nb >= 3) nb -= 3;
      STAGE(kt + 2, nb);
    }
    short8 af[4], bfr[4];
    #pragma unroll
    for (int mi = 0; mi < 4; ++mi)
      af[mi] = *(const short8*)&Abuf[cur][(wm * 64 + mi * 16 + lr) * 32 + lk];
    #pragma unroll
    for (int ni = 0; ni < 4; ++ni)
      bfr[ni] = *(const short8*)&Bbuf[cur][(wn * 64 + ni * 16 + lr) * 32 + lk];
    // drain my LDS reads, then wait next tile landed, then barrier (loads
    // for tile kt+2 remain in flight across it)
    asm volatile("s_waitcnt lgkmcnt(0)" ::: "memory");
    if (kt < 30) {
      asm volatile("s_waitcnt vmcnt(4)" ::: "memory");
    } else if (kt == 30) {
      asm volatile("s_waitcnt vmcnt(0)" ::: "memory");
    }
    __builtin_amdgcn_sched_barrier(0);
    __builtin_amdgcn_s_barrier();
    #pragma unroll
    for (int mi = 0; mi < 4; ++mi)
      #pragma unroll
      for (int ni = 0; ni < 4; ++ni)
        acc[mi][ni] = __builtin_amdgcn_mfma_f32_16x16x32_bf16(
            af[mi], bfr[ni], acc[mi][ni], 0, 0, 0);
    cur += 1; if (cur >= 3) cur = 0;
  }
#undef STAGE

  // epilogue: sup = acc + bmix  (mix folded into Wt)
  #pragma unroll
  for (int ni = 0; ni < 4; ++ni) {
    const int n = n0 + wn * 64 + ni * 16 + lr;
    const float bv = bmix[n];
    #pragma unroll
    for (int mi = 0; mi < 4; ++mi) {
      const int m = m0 + wm * 64 + mi * 16 + (lane >> 4) * 4;
      #pragma unroll
      for (int r = 0; r < 4; ++r) {
        float v = acc[mi][ni][r] + bv;
        if (BF16SUP)
          sup[(size_t)(m + r) * 16384 + n] = f2bf(v);
        else
          outf[(size_t)(m + r) * 16384 + n] = v;
      }
    }
  }
}

// ------------------------------------------------------- LN from bf16 sup
__global__ __launch_bounds__(256) void ln_bf16_kernel(
    const unsigned short* __restrict__ sup, float* __restrict__ out,
    const float* __restrict__ gamma, const float* __restrict__ beta) {
  __shared__ float red[8];
  const int t = threadIdx.x;
  const size_t base = (size_t)blockIdx.x * 1024;
  u16x4 raw = *(const u16x4*)(sup + base + t * 4);
  float v[4];
  #pragma unroll
  for (int j = 0; j < 4; ++j) v[j] = bf2f(raw[j]);
  float s = v[0] + v[1] + v[2] + v[3];
  float ss = v[0] * v[0] + v[1] * v[1] + v[2] * v[2] + v[3] * v[3];
  #pragma unroll
  for (int m = 32; m >= 1; m >>= 1) {
    s += __shfl_xor(s, m);
    ss += __shfl_xor(ss, m);
  }
  const int wv = t >> 6;
  if ((t & 63) == 0) { red[wv * 2] = s; red[wv * 2 + 1] = ss; }
  __syncthreads();
  const float S = red[0] + red[2] + red[4] + red[6];
  const float SS = red[1] + red[3] + red[5] + red[7];
  const float mean = S * (1.0f / 1024.0f);
  const float var = SS * (1.0f / 1024.0f) - mean * mean;
  const float rstd = rsqrtf(var + 1e-5f);
  const float4 g = *(const float4*)(gamma + t * 4);
  const float4 b = *(const float4*)(beta + t * 4);
  float4 o;
  o.x = (v[0] - mean) * rstd * g.x + b.x;
  o.y = (v[1] - mean) * rstd * g.y + b.y;
  o.z = (v[2] - mean) * rstd * g.z + b.z;
  o.w = (v[3] - mean) * rstd * g.w + b.w;
  *(float4*)(out + base + t * 4) = o;
}

// ------------------------------------------------------- in-place f32 LN
__global__ __launch_bounds__(256) void ln_kernel(float* __restrict__ out,
                                                 const float* __restrict__ gamma,
                                                 const float* __restrict__ beta) {
  __shared__ float red[8];
  const int t = threadIdx.x;
  const size_t base = (size_t)blockIdx.x * 1024;
  float4 v = *(const float4*)(out + base + t * 4);
  float s = v.x + v.y + v.z + v.w;
  float ss = v.x * v.x + v.y * v.y + v.z * v.z + v.w * v.w;
  #pragma unroll
  for (int m = 32; m >= 1; m >>= 1) {
    s += __shfl_xor(s, m);
    ss += __shfl_xor(ss, m);
  }
  const int wv = t >> 6;
  if ((t & 63) == 0) { red[wv * 2] = s; red[wv * 2 + 1] = ss; }
  __syncthreads();
  const float S = red[0] + red[2] + red[4] + red[6];
  const float SS = red[1] + red[3] + red[5] + red[7];
  const float mean = S * (1.0f / 1024.0f);
  const float var = SS * (1.0f / 1024.0f) - mean * mean;
  const float rstd = rsqrtf(var + 1e-5f);
  const float4 g = *(const float4*)(gamma + t * 4);
  const float4 b = *(const float4*)(beta + t * 4);
  float4 o;
  o.x = (v.x - mean) * rstd * g.x + b.x;
  o.y = (v.y - mean) * rstd * g.y + b.y;
  o.z = (v.z - mean) * rstd * g.z + b.z;
  o.w = (v.w - mean) * rstd * g.w + b.w;
  *(float4*)(out + base + t * 4) = o;
}

extern "C" void kernel_launch(void* const* d_in, const int* in_sizes, int n_in,
                              void* d_out, int out_size, void* d_ws, size_t ws_size,
                              hipStream_t stream) {
  (void)in_sizes; (void)n_in; (void)out_size;
  const float* x     = (const float*)d_in[0];  // [4096,1024]
  const float* W     = (const float*)d_in[1];  // [16,1024,1024]
  const float* bias  = (const float*)d_in[2];  // [16,1024]
  const float* amp   = (const float*)d_in[3];  // [16,1024]
  const float* phase = (const float*)d_in[4];  // [16,1024]
  const float* gamma = (const float*)d_in[5];  // [1024]
  const float* beta  = (const float*)d_in[6];  // [1024]
  float* out = (float*)d_out;                  // [4096,16,1024] = 256 MiB

  const bool big = ws_size >= (size_t)134217728ULL;  // bf16 sup fits in ws

  unsigned short *Wt, *xbuf, *supb = nullptr;
  float *mixp, *bmixp;
  if (big) {
    // scratch Wt/xb/mix live in d_out (fully rewritten by LN afterwards);
    // ws holds bf16 sup (exactly 128 MiB)
    char* ob = (char*)d_out;
    Wt    = (unsigned short*)ob;                    // 32 MiB
    xbuf  = (unsigned short*)(ob + 33554432);       //  8 MiB
    mixp  = (float*)(ob + 41943040);                // 64 KiB
    bmixp = mixp + 16384;                           // 64 KiB
    supb  = (unsigned short*)d_ws;                  // 128 MiB
  } else {
    char* ws = (char*)d_ws;
    Wt    = (unsigned short*)ws;
    xbuf  = (unsigned short*)(ws + 33554432);
    mixp  = (float*)(ws + 33554432 + 8388608);
    bmixp = mixp + 16384;
  }

  hipLaunchKernelGGL(mix_kernel, dim3(4), dim3(256), 0, stream, amp, phase, bias, mixp, bmixp);
  hipLaunchKernelGGL(cast_x_kernel, dim3(4096), dim3(256), 0, stream, x, xbuf);
  hipLaunchKernelGGL(transpose_w_kernel, dim3(16, 16, 16), dim3(256), 0, stream, W, mixp, Wt);
  if (big) {
    hipLaunchKernelGGL((gemm_kernel<true>), dim3(128, 32), dim3(256), 0, stream,
                       xbuf, Wt, bmixp, out, supb);
    hipLaunchKernelGGL(ln_bf16_kernel, dim3(65536), dim3(256), 0, stream,
                       supb, out, gamma, beta);
  } else {
    hipLaunchKernelGGL((gemm_kernel<false>), dim3(128, 32), dim3(256), 0, stream,
                       xbuf, Wt, bmixp, out, nullptr);
    hipLaunchKernelGGL(ln_kernel, dim3(65536), dim3(256), 0, stream, out, gamma, beta);
  }
}

// Round 15
// 278.031 us; speedup vs baseline: 1.4924x; 1.0769x over previous
//
#include <hip/hip_runtime.h>

typedef __attribute__((ext_vector_type(8))) short short8;
typedef __attribute__((ext_vector_type(4))) float f32x4;
typedef __attribute__((ext_vector_type(4))) unsigned short u16x4;

#define GLOAD16(g, l)                                                          \
  __builtin_amdgcn_global_load_lds(                                            \
      (const __attribute__((address_space(1))) unsigned int*)(g),              \
      (__attribute__((address_space(3))) unsigned int*)(l), 16, 0, 0)

__device__ __forceinline__ unsigned short f2bf(float f) {
  unsigned int u = __float_as_uint(f);
  u += 0x7FFFu + ((u >> 16) & 1u);   // RNE
  return (unsigned short)(u >> 16);
}
__device__ __forceinline__ float bf2f(unsigned short h) {
  return __uint_as_float(((unsigned int)h) << 16);
}

// ---------------------------------------------------------------- mix / bmix
__global__ void mix_kernel(const float* __restrict__ amp,
                           const float* __restrict__ phase,
                           const float* __restrict__ bias,
                           float* __restrict__ mix, float* __restrict__ bmix) {
  int q = blockIdx.x * blockDim.x + threadIdx.x;  // 0..1023
  float a[16];
  float mx = -1e30f;
  for (int s = 0; s < 16; ++s) {
    a[s] = amp[s * 1024 + q];
    mx = fmaxf(mx, a[s]);
  }
  float sum = 0.f;
  for (int s = 0; s < 16; ++s) {
    a[s] = __expf(a[s] - mx);
    sum += a[s];
  }
  float inv = 1.f / sum;
  for (int s = 0; s < 16; ++s) {
    float m = a[s] * inv * cosf(phase[s * 1024 + q]);
    mix[s * 1024 + q] = m;
    bmix[s * 1024 + q] = bias[s * 1024 + q] * m;
  }
}

// ---------------------------------------------------------------- cast x->bf16
__global__ void cast_x_kernel(const float* __restrict__ x,
                              unsigned short* __restrict__ xb) {
  int i = (blockIdx.x * blockDim.x + threadIdx.x) * 4;
  float4 v = *(const float4*)(x + i);
  union { unsigned short h[4]; uint2 u; } o;
  o.h[0] = f2bf(v.x); o.h[1] = f2bf(v.y); o.h[2] = f2bf(v.z); o.h[3] = f2bf(v.w);
  *(uint2*)(xb + i) = o.u;
}

// ------------------------------------------- transpose+cast+scale W -> Wt bf16
// Wt[s][q][i] = bf16( W[s][i][q] * mix[s][q] ).  float4 reads (16B/lane),
// packed uint2 LDS writes, short8 global writes (128B contiguous per q-row).
__global__ __launch_bounds__(256) void transpose_w_kernel(
    const float* __restrict__ W, const float* __restrict__ mix,
    unsigned short* __restrict__ Wt) {
  __shared__ unsigned short tile[64][68];   // 68-short row = 17 dwords, coprime 32
  const int s = blockIdx.z;
  const int q0 = blockIdx.x * 64, i0 = blockIdx.y * 64;
  const int t = threadIdx.x;
  const float* Ws = W + (size_t)s * 1048576;
  unsigned short* Wts = Wt + (size_t)s * 1048576;
  const int rq = (t & 15) * 4;
  const int ri = t >> 4;                    // 0..15
  const float4 mv = *(const float4*)(mix + s * 1024 + q0 + rq);
  #pragma unroll
  for (int p = 0; p < 4; ++p) {
    const int i = p * 16 + ri;
    float4 v = *(const float4*)(Ws + (size_t)(i0 + i) * 1024 + q0 + rq);
    union { unsigned short h[4]; uint2 u; } pk;
    pk.h[0] = f2bf(v.x * mv.x);
    pk.h[1] = f2bf(v.y * mv.y);
    pk.h[2] = f2bf(v.z * mv.z);
    pk.h[3] = f2bf(v.w * mv.w);
    *(uint2*)&tile[i][rq] = pk.u;
  }
  __syncthreads();
  const int wq = t >> 2;                    // 0..63
  const int wi = (t & 3) * 16;              // 0,16,32,48
  union { unsigned short h[8]; short8 v8; } u0, u1;
  #pragma unroll
  for (int e = 0; e < 8; ++e) {
    u0.h[e] = tile[wi + e][wq];
    u1.h[e] = tile[wi + 8 + e][wq];
  }
  unsigned short* dst = Wts + (size_t)(q0 + wq) * 1024 + i0 + wi;
  *(short8*)dst = u0.v8;
  *(short8*)(dst + 8) = u1.v8;
}

// ---------------------------------------------------------------- bf16 GEMM
// R15: R9 schedule verbatim (3-buffer depth-2, counted vmcnt held across raw
// s_barrier) at tile 128x256, BK=32, 512 threads (8 waves 2Mx4N, wave-tile
// 64x64 — per-wave code identical to R9).  Changes vs R9: FLOP/staged-byte
// 64->85 (staged total 2.1->1.5 GB), MFMA/barrier/block 64->128, LDS 72KB ->
// 2 blocks/CU (16 waves).  3 loads per STAGE -> steady vmcnt(3).
template <bool BF16SUP>
__global__ __launch_bounds__(512) void gemm_kernel(
    const unsigned short* __restrict__ xb, const unsigned short* __restrict__ wt,
    const float* __restrict__ bmix,
    float* __restrict__ outf, unsigned short* __restrict__ sup) {
  __shared__ __align__(16) unsigned short Abuf[3][128 * 32];
  __shared__ __align__(16) unsigned short Bbuf[3][256 * 32];

  const int tid = threadIdx.x;
  const int lane = tid & 63;
  const int wv = tid >> 6;                 // 0..7
  const int wm = wv >> 2, wn = wv & 3;     // 2M x 4N, wave-tile 64x64
  const int m0 = blockIdx.y * 128;
  const int n0 = blockIdx.x * 256;

  // A staging: chunk tid covers row tid>>2, 8 bf16 at col (tid&3)*8
  const int rA = tid >> 2, kA = (tid & 3) * 8;
  const unsigned short* gA = xb + (size_t)(m0 + rA) * 1024 + kA;
  // B staging: chunks tid and tid+512
  const int cB0 = tid, cB1 = tid + 512;
  const int rB0 = cB0 >> 2, kB0 = (cB0 & 3) * 8;
  const int rB1 = cB1 >> 2, kB1 = (cB1 & 3) * 8;
  const unsigned short* gB0 = wt + (size_t)(n0 + rB0) * 1024 + kB0;
  const unsigned short* gB1 = wt + (size_t)(n0 + rB1) * 1024 + kB1;

#define STAGE(kt, b) do {                                                      \
    const int _ko = (kt) * 32;                                                 \
    GLOAD16(gA + _ko, &Abuf[b][tid * 8]);                                      \
    GLOAD16(gB0 + _ko, &Bbuf[b][cB0 * 8]);                                     \
    GLOAD16(gB1 + _ko, &Bbuf[b][cB1 * 8]);                                     \
  } while (0)

  f32x4 acc[4][4];
  #pragma unroll
  for (int i = 0; i < 4; ++i)
    #pragma unroll
    for (int j = 0; j < 4; ++j) acc[i][j] = (f32x4){0.f, 0.f, 0.f, 0.f};

  // prologue: stage tiles 0,1; wait tile 0 landed (tile 1 stays in flight)
  STAGE(0, 0);
  STAGE(1, 1);
  asm volatile("s_waitcnt vmcnt(3)" ::: "memory");
  __builtin_amdgcn_s_barrier();

  const int lr = lane & 15;
  const int lk = (lane >> 4) * 8;
  int cur = 0;
  for (int kt = 0; kt < 32; ++kt) {
    if (kt < 30) {
      int nb = cur + 2; if (nb >= 3) nb -= 3;
      STAGE(kt + 2, nb);
    }
    short8 af[4], bfr[4];
    #pragma unroll
    for (int mi = 0; mi < 4; ++mi)
      af[mi] = *(const short8*)&Abuf[cur][(wm * 64 + mi * 16 + lr) * 32 + lk];
    #pragma unroll
    for (int ni = 0; ni < 4; ++ni)
      bfr[ni] = *(const short8*)&Bbuf[cur][(wn * 64 + ni * 16 + lr) * 32 + lk];
    // drain my LDS reads, then wait next tile landed, then barrier (loads
    // for tile kt+2 remain in flight across it)
    asm volatile("s_waitcnt lgkmcnt(0)" ::: "memory");
    if (kt < 30) {
      asm volatile("s_waitcnt vmcnt(3)" ::: "memory");
    } else if (kt == 30) {
      asm volatile("s_waitcnt vmcnt(0)" ::: "memory");
    }
    __builtin_amdgcn_sched_barrier(0);
    __builtin_amdgcn_s_barrier();
    #pragma unroll
    for (int mi = 0; mi < 4; ++mi)
      #pragma unroll
      for (int ni = 0; ni < 4; ++ni)
        acc[mi][ni] = __builtin_amdgcn_mfma_f32_16x16x32_bf16(
            af[mi], bfr[ni], acc[mi][ni], 0, 0, 0);
    cur += 1; if (cur >= 3) cur = 0;
  }
#undef STAGE

  // epilogue: sup = acc + bmix  (mix folded into Wt)
  #pragma unroll
  for (int ni = 0; ni < 4; ++ni) {
    const int n = n0 + wn * 64 + ni * 16 + lr;
    const float bv = bmix[n];
    #pragma unroll
    for (int mi = 0; mi < 4; ++mi) {
      const int m = m0 + wm * 64 + mi * 16 + (lane >> 4) * 4;
      #pragma unroll
      for (int r = 0; r < 4; ++r) {
        float v = acc[mi][ni][r] + bv;
        if (BF16SUP)
          sup[(size_t)(m + r) * 16384 + n] = f2bf(v);
        else
          outf[(size_t)(m + r) * 16384 + n] = v;
      }
    }
  }
}

// ------------------------------------------------------- LN from bf16 sup
// v2: 2 rows per 256-thread block, 16B/lane reads (G13 sweet spot).
__global__ __launch_bounds__(256) void ln_bf16_kernel(
    const unsigned short* __restrict__ sup, float* __restrict__ out,
    const float* __restrict__ gamma, const float* __restrict__ beta) {
  __shared__ float red[8];   // [wave][s,ss]; waves 0,1 = row 0; 2,3 = row 1
  const int t = threadIdx.x;
  const int half = t >> 7;          // row within block
  const int j = t & 127;            // 8-elem chunk index
  const size_t base = ((size_t)blockIdx.x * 2 + half) * 1024;
  union { short8 v8; unsigned short h[8]; } raw;
  raw.v8 = *(const short8*)(sup + base + j * 8);
  float v[8];
  float s = 0.f, ss = 0.f;
  #pragma unroll
  for (int e = 0; e < 8; ++e) {
    v[e] = bf2f(raw.h[e]);
    s += v[e];
    ss += v[e] * v[e];
  }
  #pragma unroll
  for (int m = 32; m >= 1; m >>= 1) {
    s += __shfl_xor(s, m);
    ss += __shfl_xor(ss, m);
  }
  const int wvi = t >> 6;
  if ((t & 63) == 0) { red[wvi * 2] = s; red[wvi * 2 + 1] = ss; }
  __syncthreads();
  const float S = red[half * 4] + red[half * 4 + 2];
  const float SS = red[half * 4 + 1] + red[half * 4 + 3];
  const float mean = S * (1.0f / 1024.0f);
  const float var = SS * (1.0f / 1024.0f) - mean * mean;
  const float rstd = rsqrtf(var + 1e-5f);
  const float4 g0 = *(const float4*)(gamma + j * 8);
  const float4 g1 = *(const float4*)(gamma + j * 8 + 4);
  const float4 b0 = *(const float4*)(beta + j * 8);
  const float4 b1 = *(const float4*)(beta + j * 8 + 4);
  float4 o0, o1;
  o0.x = (v[0] - mean) * rstd * g0.x + b0.x;
  o0.y = (v[1] - mean) * rstd * g0.y + b0.y;
  o0.z = (v[2] - mean) * rstd * g0.z + b0.z;
  o0.w = (v[3] - mean) * rstd * g0.w + b0.w;
  o1.x = (v[4] - mean) * rstd * g1.x + b1.x;
  o1.y = (v[5] - mean) * rstd * g1.y + b1.y;
  o1.z = (v[6] - mean) * rstd * g1.z + b1.z;
  o1.w = (v[7] - mean) * rstd * g1.w + b1.w;
  *(float4*)(out + base + j * 8) = o0;
  *(float4*)(out + base + j * 8 + 4) = o1;
}

// ------------------------------------------------------- in-place f32 LN
__global__ __launch_bounds__(256) void ln_kernel(float* __restrict__ out,
                                                 const float* __restrict__ gamma,
                                                 const float* __restrict__ beta) {
  __shared__ float red[8];
  const int t = threadIdx.x;
  const size_t base = (size_t)blockIdx.x * 1024;
  float4 v = *(const float4*)(out + base + t * 4);
  float s = v.x + v.y + v.z + v.w;
  float ss = v.x * v.x + v.y * v.y + v.z * v.z + v.w * v.w;
  #pragma unroll
  for (int m = 32; m >= 1; m >>= 1) {
    s += __shfl_xor(s, m);
    ss += __shfl_xor(ss, m);
  }
  const int wv = t >> 6;
  if ((t & 63) == 0) { red[wv * 2] = s; red[wv * 2 + 1] = ss; }
  __syncthreads();
  const float S = red[0] + red[2] + red[4] + red[6];
  const float SS = red[1] + red[3] + red[5] + red[7];
  const float mean = S * (1.0f / 1024.0f);
  const float var = SS * (1.0f / 1024.0f) - mean * mean;
  const float rstd = rsqrtf(var + 1e-5f);
  const float4 g = *(const float4*)(gamma + t * 4);
  const float4 b = *(const float4*)(beta + t * 4);
  float4 o;
  o.x = (v.x - mean) * rstd * g.x + b.x;
  o.y = (v.y - mean) * rstd * g.y + b.y;
  o.z = (v.z - mean) * rstd * g.z + b.z;
  o.w = (v.w - mean) * rstd * g.w + b.w;
  *(float4*)(out + base + t * 4) = o;
}

extern "C" void kernel_launch(void* const* d_in, const int* in_sizes, int n_in,
                              void* d_out, int out_size, void* d_ws, size_t ws_size,
                              hipStream_t stream) {
  (void)in_sizes; (void)n_in; (void)out_size;
  const float* x     = (const float*)d_in[0];  // [4096,1024]
  const float* W     = (const float*)d_in[1];  // [16,1024,1024]
  const float* bias  = (const float*)d_in[2];  // [16,1024]
  const float* amp   = (const float*)d_in[3];  // [16,1024]
  const float* phase = (const float*)d_in[4];  // [16,1024]
  const float* gamma = (const float*)d_in[5];  // [1024]
  const float* beta  = (const float*)d_in[6];  // [1024]
  float* out = (float*)d_out;                  // [4096,16,1024] = 256 MiB

  const bool big = ws_size >= (size_t)134217728ULL;  // bf16 sup fits in ws

  unsigned short *Wt, *xbuf, *supb = nullptr;
  float *mixp, *bmixp;
  if (big) {
    // scratch Wt/xb/mix live in d_out (fully rewritten by LN afterwards);
    // ws holds bf16 sup (exactly 128 MiB)
    char* ob = (char*)d_out;
    Wt    = (unsigned short*)ob;                    // 32 MiB
    xbuf  = (unsigned short*)(ob + 33554432);       //  8 MiB
    mixp  = (float*)(ob + 41943040);                // 64 KiB
    bmixp = mixp + 16384;                           // 64 KiB
    supb  = (unsigned short*)d_ws;                  // 128 MiB
  } else {
    char* ws = (char*)d_ws;
    Wt    = (unsigned short*)ws;
    xbuf  = (unsigned short*)(ws + 33554432);
    mixp  = (float*)(ws + 33554432 + 8388608);
    bmixp = mixp + 16384;
  }

  hipLaunchKernelGGL(mix_kernel, dim3(4), dim3(256), 0, stream, amp, phase, bias, mixp, bmixp);
  hipLaunchKernelGGL(cast_x_kernel, dim3(4096), dim3(256), 0, stream, x, xbuf);
  hipLaunchKernelGGL(transpose_w_kernel, dim3(16, 16, 16), dim3(256), 0, stream, W, mixp, Wt);
  if (big) {
    hipLaunchKernelGGL((gemm_kernel<true>), dim3(64, 32), dim3(512), 0, stream,
                       xbuf, Wt, bmixp, out, supb);
    hipLaunchKernelGGL(ln_bf16_kernel, dim3(32768), dim3(256), 0, stream,
                       supb, out, gamma, beta);
  } else {
    hipLaunchKernelGGL((gemm_kernel<false>), dim3(64, 32), dim3(512), 0, stream,
                       xbuf, Wt, bmixp, out, nullptr);
    hipLaunchKernelGGL(ln_kernel, dim3(65536), dim3(256), 0, stream, out, gamma, beta);
  }
}

// Round 16
// 276.172 us; speedup vs baseline: 1.5024x; 1.0067x over previous
//
#include <hip/hip_runtime.h>

typedef __attribute__((ext_vector_type(8))) short short8;
typedef __attribute__((ext_vector_type(4))) float f32x4;
typedef __attribute__((ext_vector_type(4))) unsigned short u16x4;

#define GLOAD16(g, l)                                                          \
  __builtin_amdgcn_global_load_lds(                                            \
      (const __attribute__((address_space(1))) unsigned int*)(g),              \
      (__attribute__((address_space(3))) unsigned int*)(l), 16, 0, 0)

__device__ __forceinline__ unsigned short f2bf(float f) {
  unsigned int u = __float_as_uint(f);
  u += 0x7FFFu + ((u >> 16) & 1u);   // RNE
  return (unsigned short)(u >> 16);
}
__device__ __forceinline__ float bf2f(unsigned short h) {
  return __uint_as_float(((unsigned int)h) << 16);
}

// ---------------------------------------------------------------- mix / bmix
__global__ void mix_kernel(const float* __restrict__ amp,
                           const float* __restrict__ phase,
                           const float* __restrict__ bias,
                           float* __restrict__ mix, float* __restrict__ bmix) {
  int q = blockIdx.x * blockDim.x + threadIdx.x;  // 0..1023
  float a[16];
  float mx = -1e30f;
  for (int s = 0; s < 16; ++s) {
    a[s] = amp[s * 1024 + q];
    mx = fmaxf(mx, a[s]);
  }
  float sum = 0.f;
  for (int s = 0; s < 16; ++s) {
    a[s] = __expf(a[s] - mx);
    sum += a[s];
  }
  float inv = 1.f / sum;
  for (int s = 0; s < 16; ++s) {
    float m = a[s] * inv * cosf(phase[s * 1024 + q]);
    mix[s * 1024 + q] = m;
    bmix[s * 1024 + q] = bias[s * 1024 + q] * m;
  }
}

// ---------------------------------------------------------------- cast x->bf16
__global__ void cast_x_kernel(const float* __restrict__ x,
                              unsigned short* __restrict__ xb) {
  int i = (blockIdx.x * blockDim.x + threadIdx.x) * 4;
  float4 v = *(const float4*)(x + i);
  union { unsigned short h[4]; uint2 u; } o;
  o.h[0] = f2bf(v.x); o.h[1] = f2bf(v.y); o.h[2] = f2bf(v.z); o.h[3] = f2bf(v.w);
  *(uint2*)(xb + i) = o.u;
}

// ------------------------------------------- transpose+cast+scale W -> Wt bf16
// Wt[s][q][i] = bf16( W[s][i][q] * mix[s][q] ).  float4 reads (16B/lane),
// packed uint2 LDS writes, short8 global writes (128B contiguous per q-row).
__global__ __launch_bounds__(256) void transpose_w_kernel(
    const float* __restrict__ W, const float* __restrict__ mix,
    unsigned short* __restrict__ Wt) {
  __shared__ unsigned short tile[64][68];   // 68-short row = 17 dwords, coprime 32
  const int s = blockIdx.z;
  const int q0 = blockIdx.x * 64, i0 = blockIdx.y * 64;
  const int t = threadIdx.x;
  const float* Ws = W + (size_t)s * 1048576;
  unsigned short* Wts = Wt + (size_t)s * 1048576;
  const int rq = (t & 15) * 4;
  const int ri = t >> 4;                    // 0..15
  const float4 mv = *(const float4*)(mix + s * 1024 + q0 + rq);
  #pragma unroll
  for (int p = 0; p < 4; ++p) {
    const int i = p * 16 + ri;
    float4 v = *(const float4*)(Ws + (size_t)(i0 + i) * 1024 + q0 + rq);
    union { unsigned short h[4]; uint2 u; } pk;
    pk.h[0] = f2bf(v.x * mv.x);
    pk.h[1] = f2bf(v.y * mv.y);
    pk.h[2] = f2bf(v.z * mv.z);
    pk.h[3] = f2bf(v.w * mv.w);
    *(uint2*)&tile[i][rq] = pk.u;
  }
  __syncthreads();
  const int wq = t >> 2;                    // 0..63
  const int wi = (t & 3) * 16;              // 0,16,32,48
  union { unsigned short h[8]; short8 v8; } u0, u1;
  #pragma unroll
  for (int e = 0; e < 8; ++e) {
    u0.h[e] = tile[wi + e][wq];
    u1.h[e] = tile[wi + 8 + e][wq];
  }
  unsigned short* dst = Wts + (size_t)(q0 + wq) * 1024 + i0 + wi;
  *(short8*)dst = u0.v8;
  *(short8*)(dst + 8) = u1.v8;
}

// ---------------------------------------------------------------- bf16 GEMM
// R15 (160us, 128x256, BK=32, 8 waves 2Mx4N, 3-buffer depth-2 counted vmcnt)
// + T2 bank-conflict swizzle (rule #21, pattern validated in R4):
//   stage chunk c, LDS row r: global slot = (c&3)^(r&3), LDS dst linear;
//   fragment read slot = ((lane>>4)^(lr&3))  [row&3 == lr&3 for all mi/ni].
// LDS[row][slot_l] holds global slot (slot_l ^ (r&3)); read inverts the XOR.
template <bool BF16SUP>
__global__ __launch_bounds__(512) void gemm_kernel(
    const unsigned short* __restrict__ xb, const unsigned short* __restrict__ wt,
    const float* __restrict__ bmix,
    float* __restrict__ outf, unsigned short* __restrict__ sup) {
  __shared__ __align__(16) unsigned short Abuf[3][128 * 32];
  __shared__ __align__(16) unsigned short Bbuf[3][256 * 32];

  const int tid = threadIdx.x;
  const int lane = tid & 63;
  const int wv = tid >> 6;                 // 0..7
  const int wm = wv >> 2, wn = wv & 3;     // 2M x 4N, wave-tile 64x64
  const int m0 = blockIdx.y * 128;
  const int n0 = blockIdx.x * 256;

  // A staging: chunk tid covers LDS row tid>>2; swizzled global slot
  const int rA = tid >> 2;
  const int kA = (((tid & 3) ^ (rA & 3)) * 8);
  const unsigned short* gA = xb + (size_t)(m0 + rA) * 1024 + kA;
  // B staging: chunks tid and tid+512
  const int cB0 = tid, cB1 = tid + 512;
  const int rB0 = cB0 >> 2, kB0 = (((cB0 & 3) ^ (rB0 & 3)) * 8);
  const int rB1 = cB1 >> 2, kB1 = (((cB1 & 3) ^ (rB1 & 3)) * 8);
  const unsigned short* gB0 = wt + (size_t)(n0 + rB0) * 1024 + kB0;
  const unsigned short* gB1 = wt + (size_t)(n0 + rB1) * 1024 + kB1;

#define STAGE(kt, b) do {                                                      \
    const int _ko = (kt) * 32;                                                 \
    GLOAD16(gA + _ko, &Abuf[b][tid * 8]);                                      \
    GLOAD16(gB0 + _ko, &Bbuf[b][cB0 * 8]);                                     \
    GLOAD16(gB1 + _ko, &Bbuf[b][cB1 * 8]);                                     \
  } while (0)

  f32x4 acc[4][4];
  #pragma unroll
  for (int i = 0; i < 4; ++i)
    #pragma unroll
    for (int j = 0; j < 4; ++j) acc[i][j] = (f32x4){0.f, 0.f, 0.f, 0.f};

  // prologue: stage tiles 0,1; wait tile 0 landed (tile 1 stays in flight)
  STAGE(0, 0);
  STAGE(1, 1);
  asm volatile("s_waitcnt vmcnt(3)" ::: "memory");
  __builtin_amdgcn_s_barrier();

  const int lr = lane & 15;
  const int lks = (((lane >> 4) ^ (lr & 3)) * 8);   // swizzled read slot
  int cur = 0;
  for (int kt = 0; kt < 32; ++kt) {
    if (kt < 30) {
      int nb = cur + 2; if (nb >= 3) nb -= 3;
      STAGE(kt + 2, nb);
    }
    short8 af[4], bfr[4];
    #pragma unroll
    for (int mi = 0; mi < 4; ++mi)
      af[mi] = *(const short8*)&Abuf[cur][(wm * 64 + mi * 16 + lr) * 32 + lks];
    #pragma unroll
    for (int ni = 0; ni < 4; ++ni)
      bfr[ni] = *(const short8*)&Bbuf[cur][(wn * 64 + ni * 16 + lr) * 32 + lks];
    // drain my LDS reads, then wait next tile landed, then barrier (loads
    // for tile kt+2 remain in flight across it)
    asm volatile("s_waitcnt lgkmcnt(0)" ::: "memory");
    if (kt < 30) {
      asm volatile("s_waitcnt vmcnt(3)" ::: "memory");
    } else if (kt == 30) {
      asm volatile("s_waitcnt vmcnt(0)" ::: "memory");
    }
    __builtin_amdgcn_sched_barrier(0);
    __builtin_amdgcn_s_barrier();
    #pragma unroll
    for (int mi = 0; mi < 4; ++mi)
      #pragma unroll
      for (int ni = 0; ni < 4; ++ni)
        acc[mi][ni] = __builtin_amdgcn_mfma_f32_16x16x32_bf16(
            af[mi], bfr[ni], acc[mi][ni], 0, 0, 0);
    cur += 1; if (cur >= 3) cur = 0;
  }
#undef STAGE

  // epilogue: sup = acc + bmix  (mix folded into Wt)
  #pragma unroll
  for (int ni = 0; ni < 4; ++ni) {
    const int n = n0 + wn * 64 + ni * 16 + lr;
    const float bv = bmix[n];
    #pragma unroll
    for (int mi = 0; mi < 4; ++mi) {
      const int m = m0 + wm * 64 + mi * 16 + (lane >> 4) * 4;
      #pragma unroll
      for (int r = 0; r < 4; ++r) {
        float v = acc[mi][ni][r] + bv;
        if (BF16SUP)
          sup[(size_t)(m + r) * 16384 + n] = f2bf(v);
        else
          outf[(size_t)(m + r) * 16384 + n] = v;
      }
    }
  }
}

// ------------------------------------------------------- LN from bf16 sup
// v2: 2 rows per 256-thread block, 16B/lane reads (G13 sweet spot).
__global__ __launch_bounds__(256) void ln_bf16_kernel(
    const unsigned short* __restrict__ sup, float* __restrict__ out,
    const float* __restrict__ gamma, const float* __restrict__ beta) {
  __shared__ float red[8];   // [wave][s,ss]; waves 0,1 = row 0; 2,3 = row 1
  const int t = threadIdx.x;
  const int half = t >> 7;          // row within block
  const int j = t & 127;            // 8-elem chunk index
  const size_t base = ((size_t)blockIdx.x * 2 + half) * 1024;
  union { short8 v8; unsigned short h[8]; } raw;
  raw.v8 = *(const short8*)(sup + base + j * 8);
  float v[8];
  float s = 0.f, ss = 0.f;
  #pragma unroll
  for (int e = 0; e < 8; ++e) {
    v[e] = bf2f(raw.h[e]);
    s += v[e];
    ss += v[e] * v[e];
  }
  #pragma unroll
  for (int m = 32; m >= 1; m >>= 1) {
    s += __shfl_xor(s, m);
    ss += __shfl_xor(ss, m);
  }
  const int wvi = t >> 6;
  if ((t & 63) == 0) { red[wvi * 2] = s; red[wvi * 2 + 1] = ss; }
  __syncthreads();
  const float S = red[half * 4] + red[half * 4 + 2];
  const float SS = red[half * 4 + 1] + red[half * 4 + 3];
  const float mean = S * (1.0f / 1024.0f);
  const float var = SS * (1.0f / 1024.0f) - mean * mean;
  const float rstd = rsqrtf(var + 1e-5f);
  const float4 g0 = *(const float4*)(gamma + j * 8);
  const float4 g1 = *(const float4*)(gamma + j * 8 + 4);
  const float4 b0 = *(const float4*)(beta + j * 8);
  const float4 b1 = *(const float4*)(beta + j * 8 + 4);
  float4 o0, o1;
  o0.x = (v[0] - mean) * rstd * g0.x + b0.x;
  o0.y = (v[1] - mean) * rstd * g0.y + b0.y;
  o0.z = (v[2] - mean) * rstd * g0.z + b0.z;
  o0.w = (v[3] - mean) * rstd * g0.w + b0.w;
  o1.x = (v[4] - mean) * rstd * g1.x + b1.x;
  o1.y = (v[5] - mean) * rstd * g1.y + b1.y;
  o1.z = (v[6] - mean) * rstd * g1.z + b1.z;
  o1.w = (v[7] - mean) * rstd * g1.w + b1.w;
  *(float4*)(out + base + j * 8) = o0;
  *(float4*)(out + base + j * 8 + 4) = o1;
}

// ------------------------------------------------------- in-place f32 LN
__global__ __launch_bounds__(256) void ln_kernel(float* __restrict__ out,
                                                 const float* __restrict__ gamma,
                                                 const float* __restrict__ beta) {
  __shared__ float red[8];
  const int t = threadIdx.x;
  const size_t base = (size_t)blockIdx.x * 1024;
  float4 v = *(const float4*)(out + base + t * 4);
  float s = v.x + v.y + v.z + v.w;
  float ss = v.x * v.x + v.y * v.y + v.z * v.z + v.w * v.w;
  #pragma unroll
  for (int m = 32; m >= 1; m >>= 1) {
    s += __shfl_xor(s, m);
    ss += __shfl_xor(ss, m);
  }
  const int wv = t >> 6;
  if ((t & 63) == 0) { red[wv * 2] = s; red[wv * 2 + 1] = ss; }
  __syncthreads();
  const float S = red[0] + red[2] + red[4] + red[6];
  const float SS = red[1] + red[3] + red[5] + red[7];
  const float mean = S * (1.0f / 1024.0f);
  const float var = SS * (1.0f / 1024.0f) - mean * mean;
  const float rstd = rsqrtf(var + 1e-5f);
  const float4 g = *(const float4*)(gamma + t * 4);
  const float4 b = *(const float4*)(beta + t * 4);
  float4 o;
  o.x = (v.x - mean) * rstd * g.x + b.x;
  o.y = (v.y - mean) * rstd * g.y + b.y;
  o.z = (v.z - mean) * rstd * g.z + b.z;
  o.w = (v.w - mean) * rstd * g.w + b.w;
  *(float4*)(out + base + t * 4) = o;
}

extern "C" void kernel_launch(void* const* d_in, const int* in_sizes, int n_in,
                              void* d_out, int out_size, void* d_ws, size_t ws_size,
                              hipStream_t stream) {
  (void)in_sizes; (void)n_in; (void)out_size;
  const float* x     = (const float*)d_in[0];  // [4096,1024]
  const float* W     = (const float*)d_in[1];  // [16,1024,1024]
  const float* bias  = (const float*)d_in[2];  // [16,1024]
  const float* amp   = (const float*)d_in[3];  // [16,1024]
  const float* phase = (const float*)d_in[4];  // [16,1024]
  const float* gamma = (const float*)d_in[5];  // [1024]
  const float* beta  = (const float*)d_in[6];  // [1024]
  float* out = (float*)d_out;                  // [4096,16,1024] = 256 MiB

  const bool big = ws_size >= (size_t)134217728ULL;  // bf16 sup fits in ws

  unsigned short *Wt, *xbuf, *supb = nullptr;
  float *mixp, *bmixp;
  if (big) {
    // scratch Wt/xb/mix live in d_out (fully rewritten by LN afterwards);
    // ws holds bf16 sup (exactly 128 MiB)
    char* ob = (char*)d_out;
    Wt    = (unsigned short*)ob;                    // 32 MiB
    xbuf  = (unsigned short*)(ob + 33554432);       //  8 MiB
    mixp  = (float*)(ob + 41943040);                // 64 KiB
    bmixp = mixp + 16384;                           // 64 KiB
    supb  = (unsigned short*)d_ws;                  // 128 MiB
  } else {
    char* ws = (char*)d_ws;
    Wt    = (unsigned short*)ws;
    xbuf  = (unsigned short*)(ws + 33554432);
    mixp  = (float*)(ws + 33554432 + 8388608);
    bmixp = mixp + 16384;
  }

  hipLaunchKernelGGL(mix_kernel, dim3(4), dim3(256), 0, stream, amp, phase, bias, mixp, bmixp);
  hipLaunchKernelGGL(cast_x_kernel, dim3(4096), dim3(256), 0, stream, x, xbuf);
  hipLaunchKernelGGL(transpose_w_kernel, dim3(16, 16, 16), dim3(256), 0, stream, W, mixp, Wt);
  if (big) {
    hipLaunchKernelGGL((gemm_kernel<true>), dim3(64, 32), dim3(512), 0, stream,
                       xbuf, Wt, bmixp, out, supb);
    hipLaunchKernelGGL(ln_bf16_kernel, dim3(32768), dim3(256), 0, stream,
                       supb, out, gamma, beta);
  } else {
    hipLaunchKernelGGL((gemm_kernel<false>), dim3(64, 32), dim3(512), 0, stream,
                       xbuf, Wt, bmixp, out, nullptr);
    hipLaunchKernelGGL(ln_kernel, dim3(65536), dim3(256), 0, stream, out, gamma, beta);
  }
}